// Round 6
// baseline (39.289 us; speedup 1.0000x reference)
//
#include <hip/hip_runtime.h>

// ResonantHTT embedding, bucketed by p01 so T stays in registers.
//   T[p01][b][u] = sum_a core0[i0,0,a,D0]*cos(phase[a]) * core1[i1,a,b,d1]
//   F[p23][b][v] = sum_c core2[i2,b,c,d2] * core3[i3,c,0,d3]
//   out[n, u*16+v] = sum_b T[id>>8][b][u] * F[id&255][b][v]
// k_tables: build T (1MB) + F (256KB), zero bucket counts.
// k_bucket: scatter tokens into p01 buckets (order non-deterministic, but
//           each token's output depends only on its own id -> d_out identical).
// k_out5:  block = (p01, chunk); wave holds T-slice in 64 VGPR, loops over
//          its bucket tokens: 1 coalesced 1KB F-load -> wave-private LDS ->
//          ds_read broadcast per b; 4 full-line nontemporal 1KB stores.

typedef float f32x4 __attribute__((ext_vector_type(4)));

#define NB  256
#define CAP 2048

__global__ __launch_bounds__(256) void k_tables(
    const float* __restrict__ core0, const float* __restrict__ core1,
    const float* __restrict__ core2, const float* __restrict__ core3,
    const float* __restrict__ phase,
    float* __restrict__ T, float* __restrict__ F, int* __restrict__ counts)
{
  if (blockIdx.x == 1279) counts[threadIdx.x] = 0;   // zero bucket counters
  const int gid = blockIdx.x * 256 + threadIdx.x;
  const int lane = threadIdx.x & 63;
  const float cown = cosf(phase[lane & 15]);         // cos(phase) per 16-lane seg
  if (blockIdx.x < 1024) {
    // ---- T: 262144 outputs, one per thread, b-major coalesced write ----
    const int p01 = gid >> 10, r = gid & 1023;
    const int b = r >> 6, u = r & 63;
    const int D0 = u >> 3, d1 = u & 7;
    const int i0 = p01 >> 4, i1 = p01 & 15;
    const float* c0 = core0 + i0 * 128 + D0;          // [a] stride 8
    const float* c1 = core1 + i1 * 2048 + b * 8 + d1; // [a] stride 128
    float acc = 0.f;
    #pragma unroll
    for (int a = 0; a < 16; ++a) {
      const float ca = __shfl(cown, a, 16);
      acc += c0[a * 8] * ca * c1[a * 128];
    }
    T[p01 * 1024 + b * 64 + u] = acc;
  } else {
    // ---- F: 65536 outputs, one per thread, b-major coalesced write ----
    const int o = gid - 262144;
    const int p23 = o >> 8, r = o & 255;
    const int b = r >> 4, v = r & 15;
    const int d2 = v >> 2, d3 = v & 3;
    const int i2 = p23 >> 4, i3 = p23 & 15;
    const float* c2 = core2 + i2 * 1024 + b * 64 + d2; // [c] stride 4
    const float* c3 = core3 + i3 * 64 + d3;            // [c] stride 4
    float acc = 0.f;
    #pragma unroll
    for (int c = 0; c < 16; ++c)
      acc += c2[c * 4] * c3[c * 4];
    F[p23 * 256 + b * 16 + v] = acc;
  }
}

__global__ __launch_bounds__(256) void k_bucket(
    const int* __restrict__ ids, int* __restrict__ counts,
    int* __restrict__ bucket)
{
  const int n = blockIdx.x * 256 + threadIdx.x;
  const int id = ids[n];
  const int p01 = id >> 8;
  const int slot = atomicAdd(&counts[p01], 1);
  if (slot < CAP) bucket[p01 * CAP + slot] = (n << 8) | (id & 255);
}

__global__ __launch_bounds__(256) void k_out5(
    const int* __restrict__ counts, const int* __restrict__ bucket,
    const float* __restrict__ T, const float* __restrict__ F,
    float* __restrict__ out)
{
  __shared__ float ldsF[4][256];                  // 1KB per wave
  const int p01 = blockIdx.x >> 2, c = blockIdx.x & 3;
  const int wv = threadIdx.x >> 6, lane = threadIdx.x & 63;
  const int cnt0 = counts[p01];
  const int cnt = cnt0 < CAP ? cnt0 : CAP;
  int s = c * 4 + wv;                             // wave's first slot
  if (s >= cnt) return;                           // no barriers -> safe exit
  const int ug = lane >> 2, vg = lane & 3;        // lane's 4x4 (u,v) tile

  // T-slice in registers: treg[b] = T[p01][b][ug*4 .. ug*4+3]
  f32x4 treg[16];
  const float* Tp = T + p01 * 1024 + ug * 4;
  #pragma unroll
  for (int b = 0; b < 16; ++b)
    treg[b] = *reinterpret_cast<const f32x4*>(Tp + b * 64);

  float* lf = &ldsF[wv][0];
  for (; s < cnt; s += 16) {                      // 16 waves per bucket
    const int e = bucket[p01 * CAP + s];
    const int n = e >> 8, p23 = e & 255;

    // stage F row (1KB) coalesced into this wave's LDS buffer
    const f32x4 fl = *reinterpret_cast<const f32x4*>(F + p23 * 256 + lane * 4);
    *reinterpret_cast<f32x4*>(lf + lane * 4) = fl;
    // intra-wave RAW on LDS: compiler emits lgkmcnt wait; no barrier needed

    float acc[4][4];
    #pragma unroll
    for (int i = 0; i < 4; ++i)
      #pragma unroll
      for (int j = 0; j < 4; ++j) acc[i][j] = 0.f;

    #pragma unroll
    for (int b = 0; b < 16; ++b) {
      const f32x4 f = *reinterpret_cast<const f32x4*>(lf + b * 16 + vg * 4);
      const f32x4 t = treg[b];
      acc[0][0] += t.x*f.x; acc[0][1] += t.x*f.y; acc[0][2] += t.x*f.z; acc[0][3] += t.x*f.w;
      acc[1][0] += t.y*f.x; acc[1][1] += t.y*f.y; acc[1][2] += t.y*f.z; acc[1][3] += t.y*f.w;
      acc[2][0] += t.z*f.x; acc[2][1] += t.z*f.y; acc[2][2] += t.z*f.z; acc[2][3] += t.z*f.w;
      acc[3][0] += t.w*f.x; acc[3][1] += t.w*f.y; acc[3][2] += t.w*f.z; acc[3][3] += t.w*f.w;
    }

    // 4 store instrs, each 64 lanes x 16B = 16 fully-covered 64B lines
    float* op = out + (size_t)n * 1024 + ug * 64 + vg * 4;
    #pragma unroll
    for (int i = 0; i < 4; ++i) {
      f32x4 v4 = { acc[i][0], acc[i][1], acc[i][2], acc[i][3] };
      __builtin_nontemporal_store(v4, reinterpret_cast<f32x4*>(op + i * 16));
    }
  }
}

extern "C" void kernel_launch(void* const* d_in, const int* in_sizes, int n_in,
                              void* d_out, int out_size, void* d_ws, size_t ws_size,
                              hipStream_t stream) {
  const int*   ids   = (const int*)  d_in[0];
  const float* core0 = (const float*)d_in[1];
  const float* core1 = (const float*)d_in[2];
  const float* core2 = (const float*)d_in[3];
  const float* core3 = (const float*)d_in[4];
  const float* phase = (const float*)d_in[5];
  float* out = (float*)d_out;

  float* Tt     = (float*)d_ws;                  // 1 MB
  float* Ft     = Tt + 262144;                   // 256 KB
  int*   counts = (int*)(Ft + 65536);            // 1 KB
  int*   bucket = counts + NB;                   // 2 MB

  const int tokens = in_sizes[0];                // 16384
  hipLaunchKernelGGL(k_tables, dim3(1280), dim3(256), 0, stream,
                     core0, core1, core2, core3, phase, Tt, Ft, counts);
  hipLaunchKernelGGL(k_bucket, dim3(tokens / 256), dim3(256), 0, stream,
                     ids, counts, bucket);
  hipLaunchKernelGGL(k_out5, dim3(NB * 4), dim3(256), 0, stream,
                     counts, bucket, Tt, Ft, out);
}

// Round 9
// 33.812 us; speedup vs baseline: 1.1620x; 1.1620x over previous
//
#include <hip/hip_runtime.h>

// ResonantHTT embedding via two pair tables (b-major layout):
//   T[p01][b][u] = sum_a core0[i0,0,a,D0]*cos(phase[a]) * core1[i1,a,b,d1]
//       p01 = i0*16+i1, u = D0*8+d1   -> 256 x 16 x 64 f32 = 1 MB
//   F[p23][b][v] = sum_c core2[i2,b,c,d2] * core3[i3,c,0,d3]
//       p23 = i2*16+i3, v = d2*4+d3   -> 256 x 16 x 16 f32 = 256 KB
// Per token: out[n, u*16+v] = sum_b T[p01][b][u] * F[p23][b][v]
// k_out6: one token per wave; operand delivery via wave-private LDS:
// 5 coalesced VMEM loads stage T-row (4KB, 4 instrs) + F-row (1KB, 1 instr);
// per-b operands come from ds_read_b128 broadcasts. __syncthreads() between
// stage and use. VMEM per token: 9 instrs (5 loads + 4 full-line NT stores).

typedef float f32x4 __attribute__((ext_vector_type(4)));

__global__ __launch_bounds__(256) void k_tables(
    const float* __restrict__ core0, const float* __restrict__ core1,
    const float* __restrict__ core2, const float* __restrict__ core3,
    const float* __restrict__ phase,
    float* __restrict__ T, float* __restrict__ F)
{
  const int gid = blockIdx.x * 256 + threadIdx.x;
  const int lane = threadIdx.x & 63;
  // each 16-lane segment holds cos(phase[0..15]); shuffle per a
  const float cown = cosf(phase[lane & 15]);
  if (blockIdx.x < 1024) {
    // ---- T: 262144 outputs, one per thread, coalesced b-major write ----
    const int p01 = gid >> 10, r = gid & 1023;
    const int b = r >> 6, u = r & 63;
    const int D0 = u >> 3, d1 = u & 7;
    const int i0 = p01 >> 4, i1 = p01 & 15;
    const float* c0 = core0 + i0 * 128 + D0;          // [a] stride 8
    const float* c1 = core1 + i1 * 2048 + b * 8 + d1; // [a] stride 128
    float acc = 0.f;
    #pragma unroll
    for (int a = 0; a < 16; ++a) {
      const float ca = __shfl(cown, a, 16);
      acc += c0[a * 8] * ca * c1[a * 128];
    }
    T[p01 * 1024 + b * 64 + u] = acc;
  } else {
    // ---- F: 65536 outputs, one per thread, coalesced b-major write ----
    const int o = gid - 262144;
    const int p23 = o >> 8, r = o & 255;
    const int b = r >> 4, v = r & 15;
    const int d2 = v >> 2, d3 = v & 3;
    const int i2 = p23 >> 4, i3 = p23 & 15;
    const float* c2 = core2 + i2 * 1024 + b * 64 + d2; // [c] stride 4
    const float* c3 = core3 + i3 * 64 + d3;            // [c] stride 4
    float acc = 0.f;
    #pragma unroll
    for (int c = 0; c < 16; ++c)
      acc += c2[c * 4] * c3[c * 4];
    F[p23 * 256 + b * 16 + v] = acc;
  }
}

__global__ __launch_bounds__(256) void k_out6(
    const int* __restrict__ ids, const float* __restrict__ T,
    const float* __restrict__ F, float* __restrict__ out)
{
  __shared__ float sT[4][1024];   // 4KB per wave
  __shared__ float sF[4][256];    // 1KB per wave
  const int wv = threadIdx.x >> 6, lane = threadIdx.x & 63;
  const int n = blockIdx.x * 4 + wv;            // one token per wave
  const int id = ids[n];                        // wave-uniform
  const int p01 = id >> 8, p23 = id & 255;
  float* tT = sT[wv];
  float* tF = sF[wv];

  // ---- stage T row (4KB): 4 coalesced 1KB loads, conflict-free LDS writes
  const float* Tp = T + p01 * 1024;
  #pragma unroll
  for (int k = 0; k < 4; ++k) {
    const f32x4 v = *reinterpret_cast<const f32x4*>(Tp + k * 256 + lane * 4);
    *reinterpret_cast<f32x4*>(tT + k * 256 + lane * 4) = v;
  }
  // ---- stage F row (1KB): ALL 64 lanes x 16B = 256 floats (R8 bug: was lane<16)
  {
    const f32x4 v = *reinterpret_cast<const f32x4*>(F + p23 * 256 + lane * 4);
    *reinterpret_cast<f32x4*>(tF + lane * 4) = v;
  }
  __syncthreads();   // cross-lane LDS RAW: required ordering point

  const int ug = lane >> 2, vg = lane & 3;      // lane's 4x4 (u,v) tile
  float acc[4][4];
  #pragma unroll
  for (int i = 0; i < 4; ++i)
    #pragma unroll
    for (int j = 0; j < 4; ++j) acc[i][j] = 0.f;

  #pragma unroll
  for (int b = 0; b < 16; ++b) {
    // 16 x 16B segments, 4-way same-addr broadcast (conflict-free)
    const f32x4 t = *reinterpret_cast<const f32x4*>(tT + b * 64 + ug * 4);
    const f32x4 f = *reinterpret_cast<const f32x4*>(tF + b * 16 + vg * 4);
    acc[0][0] += t.x*f.x; acc[0][1] += t.x*f.y; acc[0][2] += t.x*f.z; acc[0][3] += t.x*f.w;
    acc[1][0] += t.y*f.x; acc[1][1] += t.y*f.y; acc[1][2] += t.y*f.z; acc[1][3] += t.y*f.w;
    acc[2][0] += t.z*f.x; acc[2][1] += t.z*f.y; acc[2][2] += t.z*f.z; acc[2][3] += t.z*f.w;
    acc[3][0] += t.w*f.x; acc[3][1] += t.w*f.y; acc[3][2] += t.w*f.z; acc[3][3] += t.w*f.w;
  }

  // 4 store instrs, each 64 lanes x 16B = 16 fully-covered 64B lines
  float* op = out + (size_t)n * 1024 + ug * 64 + vg * 4;
  #pragma unroll
  for (int i = 0; i < 4; ++i) {
    f32x4 v4 = { acc[i][0], acc[i][1], acc[i][2], acc[i][3] };
    __builtin_nontemporal_store(v4, reinterpret_cast<f32x4*>(op + i * 16));
  }
}

extern "C" void kernel_launch(void* const* d_in, const int* in_sizes, int n_in,
                              void* d_out, int out_size, void* d_ws, size_t ws_size,
                              hipStream_t stream) {
  const int*   ids   = (const int*)  d_in[0];
  const float* core0 = (const float*)d_in[1];
  const float* core1 = (const float*)d_in[2];
  const float* core2 = (const float*)d_in[3];
  const float* core3 = (const float*)d_in[4];
  const float* phase = (const float*)d_in[5];
  float* out = (float*)d_out;

  float* Tt = (float*)d_ws;                    // 1 MB
  float* Ft = (float*)d_ws + 262144;           // 256 KB

  const int tokens = in_sizes[0];              // 16384
  hipLaunchKernelGGL(k_tables, dim3(1280), dim3(256), 0, stream,
                     core0, core1, core2, core3, phase, Tt, Ft);
  hipLaunchKernelGGL(k_out6, dim3(tokens / 4), dim3(256), 0, stream,
                     ids, Tt, Ft, out);
}

// Round 10
// 24.848 us; speedup vs baseline: 1.5812x; 1.3608x over previous
//
#include <hip/hip_runtime.h>

// ResonantHTT embedding via two pair tables (b-major layout):
//   T[p01][b][u] = sum_a core0[i0,0,a,D0]*cos(phase[a]) * core1[i1,a,b,d1]
//       p01 = i0*16+i1, u = D0*8+d1   -> 256 x 16 x 64 f32 = 1 MB
//   F[p23][b][v] = sum_c core2[i2,b,c,d2] * core3[i3,c,0,d3]
//       p23 = i2*16+i3, v = d2*4+d3   -> 256 x 16 x 16 f32 = 256 KB
// Per token: out[n, u*16+v] = sum_b T[p01][b][u] * F[p23][b][v]
// k_out7 = R4 structure + F via LDS:
//   T: 16 coalesced float4 loads into registers (4-way broadcast, L1 path)
//   F: 1 coalesced 1KB load -> wave-private LDS -> 16 ds_read_b128
//      (16-way same-address broadcast = conflict-free, LDS pipe)
//   stores: 4 full-line nontemporal 1KB stores.

typedef float f32x4 __attribute__((ext_vector_type(4)));

__global__ __launch_bounds__(256) void k_tables(
    const float* __restrict__ core0, const float* __restrict__ core1,
    const float* __restrict__ core2, const float* __restrict__ core3,
    const float* __restrict__ phase,
    float* __restrict__ T, float* __restrict__ F)
{
  const int gid = blockIdx.x * 256 + threadIdx.x;
  const int lane = threadIdx.x & 63;
  // each 16-lane segment holds cos(phase[0..15]); shuffle per a
  const float cown = cosf(phase[lane & 15]);
  if (blockIdx.x < 1024) {
    // ---- T: 262144 outputs, one per thread, coalesced b-major write ----
    const int p01 = gid >> 10, r = gid & 1023;
    const int b = r >> 6, u = r & 63;
    const int D0 = u >> 3, d1 = u & 7;
    const int i0 = p01 >> 4, i1 = p01 & 15;
    const float* c0 = core0 + i0 * 128 + D0;          // [a] stride 8
    const float* c1 = core1 + i1 * 2048 + b * 8 + d1; // [a] stride 128
    float acc = 0.f;
    #pragma unroll
    for (int a = 0; a < 16; ++a) {
      const float ca = __shfl(cown, a, 16);
      acc += c0[a * 8] * ca * c1[a * 128];
    }
    T[p01 * 1024 + b * 64 + u] = acc;
  } else {
    // ---- F: 65536 outputs, one per thread, coalesced b-major write ----
    const int o = gid - 262144;
    const int p23 = o >> 8, r = o & 255;
    const int b = r >> 4, v = r & 15;
    const int d2 = v >> 2, d3 = v & 3;
    const int i2 = p23 >> 4, i3 = p23 & 15;
    const float* c2 = core2 + i2 * 1024 + b * 64 + d2; // [c] stride 4
    const float* c3 = core3 + i3 * 64 + d3;            // [c] stride 4
    float acc = 0.f;
    #pragma unroll
    for (int c = 0; c < 16; ++c)
      acc += c2[c * 4] * c3[c * 4];
    F[p23 * 256 + b * 16 + v] = acc;
  }
}

__global__ __launch_bounds__(256) void k_out7(
    const int* __restrict__ ids, const float* __restrict__ T,
    const float* __restrict__ F, float* __restrict__ out)
{
  __shared__ float sF[4][256];                  // 1KB per wave
  const int wv = threadIdx.x >> 6, lane = threadIdx.x & 63;
  const int n = blockIdx.x * 4 + wv;            // one token per wave
  const int id = ids[n];                        // wave-uniform
  const int p01 = id >> 8, p23 = id & 255;
  const int ug = lane >> 2, vg = lane & 3;      // lane's 4x4 (u,v) tile

  // ---- T-slice into registers: 16 coalesced float4 loads (independent) ----
  f32x4 treg[16];
  const float* Tp = T + p01 * 1024 + ug * 4;
  #pragma unroll
  for (int b = 0; b < 16; ++b)
    treg[b] = *reinterpret_cast<const f32x4*>(Tp + b * 64);

  // ---- F-row (1KB): ONE coalesced load -> wave-private LDS ----
  float* tF = sF[wv];
  {
    const f32x4 v = *reinterpret_cast<const f32x4*>(F + p23 * 256 + lane * 4);
    *reinterpret_cast<f32x4*>(tF + lane * 4) = v;
  }
  __syncthreads();   // cross-lane LDS RAW ordering (required, R7 lesson)

  float acc[4][4];
  #pragma unroll
  for (int i = 0; i < 4; ++i)
    #pragma unroll
    for (int j = 0; j < 4; ++j) acc[i][j] = 0.f;

  #pragma unroll
  for (int b = 0; b < 16; ++b) {
    // 4 distinct 16B segments (16 banks), 16-way same-addr broadcast: free
    const f32x4 f = *reinterpret_cast<const f32x4*>(tF + b * 16 + vg * 4);
    const f32x4 t = treg[b];
    acc[0][0] += t.x*f.x; acc[0][1] += t.x*f.y; acc[0][2] += t.x*f.z; acc[0][3] += t.x*f.w;
    acc[1][0] += t.y*f.x; acc[1][1] += t.y*f.y; acc[1][2] += t.y*f.z; acc[1][3] += t.y*f.w;
    acc[2][0] += t.z*f.x; acc[2][1] += t.z*f.y; acc[2][2] += t.z*f.z; acc[2][3] += t.z*f.w;
    acc[3][0] += t.w*f.x; acc[3][1] += t.w*f.y; acc[3][2] += t.w*f.z; acc[3][3] += t.w*f.w;
  }

  // 4 store instrs, each 64 lanes x 16B = 16 fully-covered 64B lines
  float* op = out + (size_t)n * 1024 + ug * 64 + vg * 4;
  #pragma unroll
  for (int i = 0; i < 4; ++i) {
    f32x4 v4 = { acc[i][0], acc[i][1], acc[i][2], acc[i][3] };
    __builtin_nontemporal_store(v4, reinterpret_cast<f32x4*>(op + i * 16));
  }
}

extern "C" void kernel_launch(void* const* d_in, const int* in_sizes, int n_in,
                              void* d_out, int out_size, void* d_ws, size_t ws_size,
                              hipStream_t stream) {
  const int*   ids   = (const int*)  d_in[0];
  const float* core0 = (const float*)d_in[1];
  const float* core1 = (const float*)d_in[2];
  const float* core2 = (const float*)d_in[3];
  const float* core3 = (const float*)d_in[4];
  const float* phase = (const float*)d_in[5];
  float* out = (float*)d_out;

  float* Tt = (float*)d_ws;                    // 1 MB
  float* Ft = (float*)d_ws + 262144;           // 256 KB

  const int tokens = in_sizes[0];              // 16384
  hipLaunchKernelGGL(k_tables, dim3(1280), dim3(256), 0, stream,
                     core0, core1, core2, core3, phase, Tt, Ft);
  hipLaunchKernelGGL(k_out7, dim3(tokens / 4), dim3(256), 0, stream,
                     ids, Tt, Ft, out);
}